// Round 7
// baseline (75.150 us; speedup 1.0000x reference)
//
#include <hip/hip_runtime.h>

// B=131072 points (D=16 fp32), K=256 centers. Out (fp32): [B] argmin idx ++ [B,16] offsets.
//
// Round-7 = round-6 structure with the sign bug fixed: round 6 packed y=-2x
// AND multiplied by n2c=-2c, giving c2+4*x.c (garbage argmin, absmax 254).
// Now y holds RAW x; the -2 lives only in n2c (round-1-verified formulation:
// score = c2[k] + sum x[d]*(-2c[d]) = c2 - 2*x.c; x2 per-point constant is
// argmin-invariant; strict < => lowest-k tie-break like jnp.argmin).
//
// All-SMEM k-loop: prep kernel writes n2c=-2*c and c2 into d_ws; main k-loop
// reads ONLY scalar memory (wave-uniform k -> s_load), no ds_read mixed into
// lgkmcnt inside the hot loop. LDS used solely for the post-loop cross-wave
// winner reduction. Block = 256 thr = 4 waves, 128 points (2/lane packed in
// v2f; y*c+acc contracts to v_pk_fma_f32). Wave w scans centers [64w,64w+64).

constexpr int Bn = 131072;
constexpr int Kn = 256;
constexpr int Dn = 16;
constexpr int PTS = 128;      // points per block (2 per lane)
constexpr int NW = 4;         // waves per block == K chunks
constexpr int KC = Kn / NW;   // 64 centers per wave

typedef float v2f __attribute__((ext_vector_type(2)));

__global__ __launch_bounds__(256) void prep_kernel(
    const float* __restrict__ centers, float* __restrict__ n2c,
    float* __restrict__ c2) {
  int t = blockIdx.x * 256 + threadIdx.x;
  if (t < Kn * Dn) n2c[t] = -2.0f * centers[t];
  if (t < Kn) {
    const float* c = centers + t * Dn;
    float s = 0.0f;
#pragma unroll
    for (int d = 0; d < Dn; ++d) s = fmaf(c[d], c[d], s);
    c2[t] = s;
  }
}

__global__ __launch_bounds__(256, 8) void kmeans_kernel(
    const float* __restrict__ traj, const float* __restrict__ centers,
    const float* __restrict__ n2c, const float* __restrict__ c2,
    float* __restrict__ out) {
  __shared__ float sbest[NW * PTS];
  __shared__ int sbi[NW * PTS];
  __shared__ int swin[PTS];

  const int t = threadIdx.x;
  const int blk = blockIdx.x;
  const int w = __builtin_amdgcn_readfirstlane(t >> 6);  // wave id (SGPR)
  const int l = t & 63;                                  // lane
  const int p0 = blk * PTS + l;        // this lane's point 0
  const int p1 = p0 + 64;              // this lane's point 1

  // ---- Load RAW x for both points, packed {pt0, pt1} per dim.
  v2f y[Dn];
  {
    const float4* xa = reinterpret_cast<const float4*>(traj + (size_t)p0 * Dn);
    const float4* xb = reinterpret_cast<const float4*>(traj + (size_t)p1 * Dn);
#pragma unroll
    for (int q = 0; q < 4; ++q) {
      float4 a = xa[q], b = xb[q];
      y[q * 4 + 0] = (v2f){a.x, b.x};
      y[q * 4 + 1] = (v2f){a.y, b.y};
      y[q * 4 + 2] = (v2f){a.z, b.z};
      y[q * 4 + 3] = (v2f){a.w, b.w};
    }
  }

  // ---- k-loop: SMEM only (s_load n2c row + s_load c2), no LDS.
  float best0 = __builtin_inff(), best1 = __builtin_inff();
  int bi0 = 0, bi1 = 0;
  const int k0 = w * KC;
#pragma unroll 4
  for (int kk = 0; kk < KC; ++kk) {
    const int k = k0 + kk;
    const float* cr = n2c + k * Dn;    // wave-uniform -> s_load_dwordx16
    const float c2k = c2[k];           // wave-uniform -> s_load_dword
    v2f acc = (v2f){c2k, c2k};
#pragma unroll
    for (int d = 0; d < Dn; ++d) {
      const float c = cr[d];           // SGPR; broadcast into both halves
      acc = y[d] * (v2f){c, c} + acc;  // contracts to v_pk_fma_f32
    }
    if (acc.x < best0) { best0 = acc.x; bi0 = k; }  // strict <: lowest-k ties
    if (acc.y < best1) { best1 = acc.y; bi1 = k; }
  }
  sbest[w * PTS + l] = best0;
  sbi[w * PTS + l] = bi0;
  sbest[w * PTS + 64 + l] = best1;
  sbi[w * PTS + 64 + l] = bi1;
  __syncthreads();

  // ---- Cross-wave reduction: threads 0..127, one per point. Ascending chunk
  // order + strict < keeps the lowest-k winner on exact ties.
  if (t < PTS) {
    float b0 = sbest[t];
    int i0 = sbi[t];
#pragma unroll
    for (int ww = 1; ww < NW; ++ww) {
      float b1 = sbest[ww * PTS + t];
      int i1 = sbi[ww * PTS + t];
      if (b1 < b0) { b0 = b1; i0 = i1; }
    }
    swin[t] = i0;
    out[blk * PTS + t] = (float)i0;  // idx output (fp32 buffer), coalesced
  }
  __syncthreads();

  // ---- Coalesced offset stores: 128 points x 4 quarters = 512 float4 ops.
#pragma unroll
  for (int it = 0; it < 2; ++it) {
    const int id = it * 256 + t;
    const int pb = id >> 2, q = id & 3;
    const int pt = blk * PTS + pb;
    const int win = swin[pb];
    float4 xv = reinterpret_cast<const float4*>(traj + (size_t)pt * Dn)[q];  // L1-hot
    float4 cv = reinterpret_cast<const float4*>(centers + (size_t)win * Dn)[q];
    float4 o = make_float4(xv.x - cv.x, xv.y - cv.y, xv.z - cv.z, xv.w - cv.w);
    reinterpret_cast<float4*>(out + Bn)[(size_t)pt * 4 + q] = o;
  }
}

extern "C" void kernel_launch(void* const* d_in, const int* in_sizes, int n_in,
                              void* d_out, int out_size, void* d_ws, size_t ws_size,
                              hipStream_t stream) {
  (void)in_sizes; (void)n_in; (void)out_size; (void)ws_size;
  const float* traj = (const float*)d_in[0];     // [131072, 16]
  const float* centers = (const float*)d_in[1];  // [256, 16]
  float* out = (float*)d_out;                    // [131072] idx ++ [131072*16] offsets

  float* n2c = (float*)d_ws;                     // 4096 floats
  float* c2 = n2c + Kn * Dn;                     // 256 floats

  prep_kernel<<<16, 256, 0, stream>>>(centers, n2c, c2);
  kmeans_kernel<<<Bn / PTS, 256, 0, stream>>>(traj, centers, n2c, c2, out);
}